// Round 4
// baseline (811.285 us; speedup 1.0000x reference)
//
#include <hip/hip_runtime.h>
#include <math.h>

#define D 128
#define CT 2                     // source col-tiles (of 16) per wave
#define SRCS_PER_WAVE (CT * 16)  // 32; 100000 = 3125 * 32 exactly
#define BIAS 16.0f               // keeps biased approx distance > 0 (key ordering)

typedef __attribute__((ext_vector_type(8))) short short8;   // 8 bf16 = 4 VGPR
typedef __attribute__((ext_vector_type(4))) float f32x4;

// fp32 -> bf16 bits, round-to-nearest-even
static __device__ __forceinline__ unsigned short f2bf(float x) {
    unsigned u = __float_as_uint(x);
    unsigned r = u + 0x7FFFu + ((u >> 16) & 1u);
    return (unsigned short)(r >> 16);
}

// sorted ascending top-5 insert of packed key (smaller = closer)
static __device__ __forceinline__ void ins5(unsigned st[5], unsigned key) {
    unsigned k = key, m;
    m = k > st[3] ? k : st[3]; k = k < st[3] ? k : st[3]; st[4] = m;
    m = k > st[2] ? k : st[2]; k = k < st[2] ? k : st[2]; st[3] = m;
    m = k > st[1] ? k : st[1]; k = k < st[1] ? k : st[1]; st[2] = m;
    m = k > st[0] ? k : st[0]; k = k < st[0] ? k : st[0]; st[1] = m;
    st[0] = k;
}

// Phase 0: tgt (fp32) -> tbf = bf16(-2*tgt) padded to Mpad rows (zeros),
// tsq = fp32 |t|^2 (INF for pad rows). One wave per row.
__global__ void prep_kernel(const float* __restrict__ tgt, unsigned short* __restrict__ tbf,
                            float* __restrict__ tsq, int M, int Mpad) {
    int row  = blockIdx.x;
    int lane = threadIdx.x;  // 64
    if (row >= Mpad) return;
    float2 v = make_float2(0.f, 0.f);
    if (row < M) v = *(const float2*)(tgt + (size_t)row * D + lane * 2);
    unsigned pack = (unsigned)f2bf(-2.f * v.x) | ((unsigned)f2bf(-2.f * v.y) << 16);
    *(unsigned*)(tbf + (size_t)row * D + lane * 2) = pack;
    float ss = v.x * v.x + v.y * v.y;
    #pragma unroll
    for (int off = 1; off < 64; off <<= 1) ss += __shfl_xor(ss, off);
    if (lane == 0) tsq[row] = (row < M) ? ss : __builtin_inff();
}

// Main: A = targets (rows, swept), B = sources (cols, register-resident).
// acc init = tsq[row]+BIAS; MFMA adds (-2t)·s => acc = biased shifted sq-distance.
// Per-thread per col-tile: top-5 packed keys for its row-class g = lane>>4.
// Epilogue: exact fp32 re-rank of the 20 candidates + softmax + output.
__global__ __launch_bounds__(64, 4)
void knn_kernel(const float* __restrict__ src, const unsigned short* __restrict__ tbf,
                const float* __restrict__ tsq, const float* __restrict__ tgt,
                const float* __restrict__ tpts, float* __restrict__ out,
                int N, int M, int Mpad) {
    const int lane = (int)threadIdx.x;
    const int c16  = lane & 15;   // MFMA col (source slot) / A-row within tile
    const int g    = lane >> 4;   // row-class (C rows 4g..4g+3)
    const int colbase = blockIdx.x * SRCS_PER_WAVE;

    // ---- build source (B) fragments: bf16, k = kk*32 + g*8 + e (matches A packing)
    short8 bfrag[CT][4];
    #pragma unroll
    for (int ct = 0; ct < CT; ++ct) {
        int srow = colbase + ct * 16 + c16;
        if (srow >= N) srow = N - 1;
        const float* sp = src + (size_t)srow * D + g * 8;
        #pragma unroll
        for (int kk = 0; kk < 4; ++kk) {
            float4 v0 = *(const float4*)(sp + kk * 32);
            float4 v1 = *(const float4*)(sp + kk * 32 + 4);
            short8 b;
            b[0] = (short)f2bf(v0.x); b[1] = (short)f2bf(v0.y);
            b[2] = (short)f2bf(v0.z); b[3] = (short)f2bf(v0.w);
            b[4] = (short)f2bf(v1.x); b[5] = (short)f2bf(v1.y);
            b[6] = (short)f2bf(v1.z); b[7] = (short)f2bf(v1.w);
            bfrag[ct][kk] = b;
        }
    }

    unsigned st[CT][5];
    #pragma unroll
    for (int ct = 0; ct < CT; ++ct)
        #pragma unroll
        for (int s = 0; s < 5; ++s) st[ct][s] = 0xFFFFFFFFu;

    const int steps = Mpad >> 4;
    const size_t lane_off = (size_t)c16 * D + g * 8;

    // prologue: load step 0
    short8 a[4];
    float4 qv;
    {
        const unsigned short* ap = tbf + lane_off;
        #pragma unroll
        for (int kk = 0; kk < 4; ++kk) a[kk] = *(const short8*)(ap + kk * 32);
        qv = *(const float4*)(tsq + g * 4);
    }

    unsigned jb = (unsigned)(g * 4);
    for (int t = 0; t < steps; ++t) {
        // prefetch next step (re-reads current on the final iteration; in-bounds, L2-hot)
        int tpf = t + ((t + 1) < steps ? 1 : 0);
        const unsigned short* apf = tbf + (size_t)tpf * (16 * D) + lane_off;
        short8 an[4];
        #pragma unroll
        for (int kk = 0; kk < 4; ++kk) an[kk] = *(const short8*)(apf + kk * 32);
        float4 qn = *(const float4*)(tsq + (size_t)tpf * 16 + g * 4);

        #pragma unroll
        for (int ct = 0; ct < CT; ++ct) {
            f32x4 acc = { qv.x + BIAS, qv.y + BIAS, qv.z + BIAS, qv.w + BIAS };
            #pragma unroll
            for (int kk = 0; kk < 4; ++kk)
                acc = __builtin_amdgcn_mfma_f32_16x16x32_bf16(a[kk], bfrag[ct][kk], acc, 0, 0, 0);
            #pragma unroll
            for (int e = 0; e < 4; ++e) {
                unsigned key = (__float_as_uint(acc[e]) & 0xFFFFE000u) | (jb + (unsigned)e);
                if (__builtin_expect(key < st[ct][4], 0)) ins5(st[ct], key);
            }
        }
        #pragma unroll
        for (int kk = 0; kk < 4; ++kk) a[kk] = an[kk];
        qv = qn;
        jb += 16;
    }

    // ---- exact fp32 refine of 20 candidates per source ----
    __shared__ float cd[16][20];
    __shared__ int   cj[16][20];

    #pragma unroll
    for (int ct = 0; ct < CT; ++ct) {
        int js[5]; float dots[5];
        #pragma unroll
        for (int s = 0; s < 5; ++s) {
            int j = (int)(st[ct][s] & 0x1FFFu);
            js[s] = (j < M) ? j : (M - 1);
            dots[s] = 0.f;
        }
        int srow = colbase + ct * 16 + c16;
        int srcl = (srow < N) ? srow : (N - 1);
        const float* sp = src + (size_t)srcl * D;
        for (int kc = 0; kc < D / 16; ++kc) {
            float4 s0 = *(const float4*)(sp + kc * 16);
            float4 s1 = *(const float4*)(sp + kc * 16 + 4);
            float4 s2 = *(const float4*)(sp + kc * 16 + 8);
            float4 s3 = *(const float4*)(sp + kc * 16 + 12);
            #pragma unroll
            for (int s = 0; s < 5; ++s) {
                const float* tp = tgt + (size_t)js[s] * D + kc * 16;
                float4 t0 = *(const float4*)(tp);
                float4 t1 = *(const float4*)(tp + 4);
                float4 t2 = *(const float4*)(tp + 8);
                float4 t3 = *(const float4*)(tp + 12);
                float d = dots[s];
                d = fmaf(s0.x, t0.x, d); d = fmaf(s0.y, t0.y, d);
                d = fmaf(s0.z, t0.z, d); d = fmaf(s0.w, t0.w, d);
                d = fmaf(s1.x, t1.x, d); d = fmaf(s1.y, t1.y, d);
                d = fmaf(s1.z, t1.z, d); d = fmaf(s1.w, t1.w, d);
                d = fmaf(s2.x, t2.x, d); d = fmaf(s2.y, t2.y, d);
                d = fmaf(s2.z, t2.z, d); d = fmaf(s2.w, t2.w, d);
                d = fmaf(s3.x, t3.x, d); d = fmaf(s3.y, t3.y, d);
                d = fmaf(s3.z, t3.z, d); d = fmaf(s3.w, t3.w, d);
                dots[s] = d;
            }
        }
        #pragma unroll
        for (int s = 0; s < 5; ++s) {
            cd[c16][g * 5 + s] = fmaf(-2.f, dots[s], tsq[js[s]]);
            cj[c16][g * 5 + s] = js[s];
        }
        __syncthreads();
        if (g == 0) {
            float d0 = __builtin_inff(), d1 = d0, d2 = d0;
            int i0 = 0, i1 = 0, i2 = 0;
            for (int k = 0; k < 20; ++k) {
                float dd = cd[c16][k]; int jj = cj[c16][k];
                if (dd < d2) {
                    if (dd < d1) {
                        d2 = d1; i2 = i1;
                        if (dd < d0) { d1 = d0; i1 = i0; d0 = dd; i0 = jj; }
                        else         { d1 = dd; i1 = jj; }
                    } else { d2 = dd; i2 = jj; }
                }
            }
            if (srow < N) {
                float e1 = __expf(d0 - d1);
                float e2 = __expf(d0 - d2);
                float inv = 1.f / (1.f + e1 + e2);
                float w0 = inv, w1 = e1 * inv, w2 = e2 * inv;
                const float* p0 = tpts + 3 * (size_t)i0;
                const float* p1 = tpts + 3 * (size_t)i1;
                const float* p2 = tpts + 3 * (size_t)i2;
                out[3 * (size_t)srow + 0] = w0 * p0[0] + w1 * p1[0] + w2 * p2[0];
                out[3 * (size_t)srow + 1] = w0 * p0[1] + w1 * p1[1] + w2 * p2[1];
                out[3 * (size_t)srow + 2] = w0 * p0[2] + w1 * p1[2] + w2 * p2[2];
            }
        }
        __syncthreads();
    }
}

extern "C" void kernel_launch(void* const* d_in, const int* in_sizes, int n_in,
                              void* d_out, int out_size, void* d_ws, size_t ws_size,
                              hipStream_t stream) {
    const float* src  = (const float*)d_in[0];  // [N,128]
    const float* tgt  = (const float*)d_in[1];  // [M,128]
    const float* tpts = (const float*)d_in[2];  // [M,3]
    float* out = (float*)d_out;

    int N = in_sizes[0] / D;
    int M = in_sizes[1] / D;
    int Mpad = (M + 15) & ~15;

    unsigned short* tbf = (unsigned short*)d_ws;                 // Mpad*128 bf16 (-2*t)
    float* tsq = (float*)((char*)d_ws + (size_t)Mpad * D * 2);   // Mpad f32 (INF pads)

    prep_kernel<<<Mpad, 64, 0, stream>>>(tgt, tbf, tsq, M, Mpad);
    int nblk = (N + SRCS_PER_WAVE - 1) / SRCS_PER_WAVE;          // 3125
    knn_kernel<<<nblk, 64, 0, stream>>>(src, tbf, tsq, tgt, tpts, out, N, M, Mpad);
}

// Round 5
// 686.838 us; speedup vs baseline: 1.1812x; 1.1812x over previous
//
#include <hip/hip_runtime.h>
#include <math.h>

#define D 128
#define CT 2                       // source col-tiles (of 16) per wave
#define SRCS_PER_WAVE (CT * 16)    // 32
#define WAVES 4                    // waves per block; block covers 128 sources
#define BIAS 16.0f                 // keeps biased approx distance > 0 (u32 key ordering)

typedef __attribute__((ext_vector_type(8))) short short8;   // 8 bf16 = 4 VGPR
typedef __attribute__((ext_vector_type(4))) float f32x4;

// fp32 -> bf16 bits, round-to-nearest-even
static __device__ __forceinline__ unsigned short f2bf(float x) {
    unsigned u = __float_as_uint(x);
    unsigned r = u + 0x7FFFu + ((u >> 16) & 1u);
    return (unsigned short)(r >> 16);
}

// branchless sorted-ascending top-5 insert (13 min/max ops, no divergence)
static __device__ __forceinline__ void ins5(unsigned st[5], unsigned k) {
    unsigned hi;
    hi = st[3] > k ? st[3] : k;  st[4] = st[4] < hi ? st[4] : hi;  k = st[3] < k ? st[3] : k;
    hi = st[2] > k ? st[2] : k;  st[3] = st[3] < hi ? st[3] : hi;  k = st[2] < k ? st[2] : k;
    hi = st[1] > k ? st[1] : k;  st[2] = st[2] < hi ? st[2] : hi;  k = st[1] < k ? st[1] : k;
    hi = st[0] > k ? st[0] : k;  st[1] = st[1] < hi ? st[1] : hi;  k = st[0] < k ? st[0] : k;
    st[0] = k;
}

static __device__ __forceinline__ void gload_lds16(const void* g, void* l) {
    __builtin_amdgcn_global_load_lds(
        (const __attribute__((address_space(1))) unsigned*)g,
        (__attribute__((address_space(3))) unsigned*)l, 16, 0, 0);
}

// Phase 0: tgt (fp32) -> tbf = bf16(-2*tgt), PRE-SWIZZLED within each 16-row tile:
// 16B-unit u of row r stored at unit u ^ (r&15). Pad rows (M..Mpad) are zeros.
// tsq = fp32 |t|^2 (INF for pad rows). One wave per row.
__global__ void prep_kernel(const float* __restrict__ tgt, unsigned short* __restrict__ tbf,
                            float* __restrict__ tsq, int M, int Mpad) {
    int row  = blockIdx.x;
    int lane = threadIdx.x;  // 64; handles elems 2*lane, 2*lane+1
    if (row >= Mpad) return;
    float2 v = make_float2(0.f, 0.f);
    if (row < M) v = *(const float2*)(tgt + (size_t)row * D + lane * 2);
    unsigned pack = (unsigned)f2bf(-2.f * v.x) | ((unsigned)f2bf(-2.f * v.y) << 16);
    // swizzled write: unit (lane>>2) -> (lane>>2)^(row&15), word (lane&3)
    size_t byte = (size_t)row * 256 + (size_t)(((lane >> 2) ^ (row & 15)) * 16 + (lane & 3) * 4);
    *(unsigned*)((char*)tbf + byte) = pack;
    float ss = v.x * v.x + v.y * v.y;
    #pragma unroll
    for (int off = 1; off < 64; off <<= 1) ss += __shfl_xor(ss, off);
    if (lane == 0) tsq[row] = (row < M) ? ss : __builtin_inff();
}

// Main: A = targets (16-row tiles, swept; staged to LDS once per 4-wave block),
// B = sources (cols, register-resident). acc init = tsq[row]+BIAS; MFMA adds
// (-2t)·s => acc = biased shifted sq-distance. Per-thread per col-tile: top-5
// packed keys (dist bits | 13-bit j) for its row-class g = lane>>4.
// Epilogue: exact fp32 re-rank of the 20 candidates + softmax + output.
__global__ __launch_bounds__(256, 3)
void knn_kernel(const float* __restrict__ src, const unsigned short* __restrict__ tbf,
                const float* __restrict__ tsq, const float* __restrict__ tgt,
                const float* __restrict__ tpts, float* __restrict__ out,
                int N, int M, int Mpad) {
    const int tid  = (int)threadIdx.x;
    const int wid  = tid >> 6;
    const int lane = tid & 63;
    const int c16  = lane & 15;   // MFMA col (source slot) / A-row within tile
    const int g    = lane >> 4;   // row-class (C rows 4g..4g+3)
    const int colbase = blockIdx.x * (WAVES * SRCS_PER_WAVE) + wid * SRCS_PER_WAVE;

    __shared__ short8 abuf[2][256];          // 2 x 4KB double-buffered A tile (swizzled)
    __shared__ float cdv[WAVES][16][20];
    __shared__ int   cjv[WAVES][16][20];

    // ---- build source (B) fragments: bf16, k = kk*32 + g*8 + e (matches A packing)
    short8 bfrag[CT][4];
    #pragma unroll
    for (int ct = 0; ct < CT; ++ct) {
        int srow = colbase + ct * 16 + c16;
        if (srow >= N) srow = N - 1;
        const float* sp = src + (size_t)srow * D + g * 8;
        #pragma unroll
        for (int kk = 0; kk < 4; ++kk) {
            float4 v0 = *(const float4*)(sp + kk * 32);
            float4 v1 = *(const float4*)(sp + kk * 32 + 4);
            short8 b;
            b[0] = (short)f2bf(v0.x); b[1] = (short)f2bf(v0.y);
            b[2] = (short)f2bf(v0.z); b[3] = (short)f2bf(v0.w);
            b[4] = (short)f2bf(v1.x); b[5] = (short)f2bf(v1.y);
            b[6] = (short)f2bf(v1.z); b[7] = (short)f2bf(v1.w);
            bfrag[ct][kk] = b;
        }
    }

    unsigned st[CT][5];
    #pragma unroll
    for (int ct = 0; ct < CT; ++ct)
        #pragma unroll
        for (int s = 0; s < 5; ++s) st[ct][s] = 0xFFFFFFFFu;

    const int steps = Mpad >> 4;

    // prologue: stage tile 0 (each wave stages its 1KB quarter, linear copy)
    gload_lds16((const char*)tbf + (size_t)(wid * 64 + lane) * 16, &abuf[0][wid * 64]);
    float4 qv = *(const float4*)(tsq + g * 4);
    __syncthreads();

    unsigned jb = (unsigned)(g * 4);
    int cur = 0;
    for (int t = 0; t < steps; ++t) {
        // stage next tile into the other buffer (clamped re-stage on last step)
        int tpf = (t + 1 < steps) ? (t + 1) : t;
        gload_lds16((const char*)tbf + (size_t)tpf * 4096 + (size_t)(wid * 64 + lane) * 16,
                    &abuf[cur ^ 1][wid * 64]);
        float4 qn = *(const float4*)(tsq + (size_t)tpf * 16 + g * 4);

        // A fragments from LDS (swizzled read: 2-way bank conflict max)
        short8 a[4];
        #pragma unroll
        for (int kk = 0; kk < 4; ++kk) {
            int up = (g + 4 * kk) ^ c16;
            a[kk] = abuf[cur][c16 * 16 + up];
        }

        f32x4 qb = { qv.x + BIAS, qv.y + BIAS, qv.z + BIAS, qv.w + BIAS };
        #pragma unroll
        for (int ct = 0; ct < CT; ++ct) {
            f32x4 acc = qb;
            #pragma unroll
            for (int kk = 0; kk < 4; ++kk)
                acc = __builtin_amdgcn_mfma_f32_16x16x32_bf16(a[kk], bfrag[ct][kk], acc, 0, 0, 0);
            #pragma unroll
            for (int e = 0; e < 4; ++e) {
                unsigned key = (__float_as_uint(acc[e]) & 0xFFFFE000u) | (jb + (unsigned)e);
                ins5(st[ct], key);
            }
        }
        qv = qn;
        jb += 16;
        __syncthreads();   // drains vmcnt(0): next tile staged; all reads of cur consumed
        cur ^= 1;
    }

    // ---- exact fp32 refine of 20 candidates per source ----
    #pragma unroll
    for (int ct = 0; ct < CT; ++ct) {
        int js[5]; float dots[5];
        #pragma unroll
        for (int s = 0; s < 5; ++s) {
            int j = (int)(st[ct][s] & 0x1FFFu);
            js[s] = (j < M) ? j : (M - 1);
            dots[s] = 0.f;
        }
        int srow = colbase + ct * 16 + c16;
        int srcl = (srow < N) ? srow : (N - 1);
        const float* sp = src + (size_t)srcl * D;
        for (int kc = 0; kc < D / 16; ++kc) {
            float4 s0 = *(const float4*)(sp + kc * 16);
            float4 s1 = *(const float4*)(sp + kc * 16 + 4);
            float4 s2 = *(const float4*)(sp + kc * 16 + 8);
            float4 s3 = *(const float4*)(sp + kc * 16 + 12);
            #pragma unroll
            for (int s = 0; s < 5; ++s) {
                const float* tp = tgt + (size_t)js[s] * D + kc * 16;
                float4 t0 = *(const float4*)(tp);
                float4 t1 = *(const float4*)(tp + 4);
                float4 t2 = *(const float4*)(tp + 8);
                float4 t3 = *(const float4*)(tp + 12);
                float d = dots[s];
                d = fmaf(s0.x, t0.x, d); d = fmaf(s0.y, t0.y, d);
                d = fmaf(s0.z, t0.z, d); d = fmaf(s0.w, t0.w, d);
                d = fmaf(s1.x, t1.x, d); d = fmaf(s1.y, t1.y, d);
                d = fmaf(s1.z, t1.z, d); d = fmaf(s1.w, t1.w, d);
                d = fmaf(s2.x, t2.x, d); d = fmaf(s2.y, t2.y, d);
                d = fmaf(s2.z, t2.z, d); d = fmaf(s2.w, t2.w, d);
                d = fmaf(s3.x, t3.x, d); d = fmaf(s3.y, t3.y, d);
                d = fmaf(s3.z, t3.z, d); d = fmaf(s3.w, t3.w, d);
                dots[s] = d;
            }
        }
        #pragma unroll
        for (int s = 0; s < 5; ++s) {
            cdv[wid][c16][g * 5 + s] = fmaf(-2.f, dots[s], tsq[js[s]]);
            cjv[wid][c16][g * 5 + s] = js[s];
        }
        __syncthreads();
        if (g == 0) {
            float d0 = __builtin_inff(), d1 = d0, d2 = d0;
            int i0 = 0, i1 = 0, i2 = 0;
            for (int k = 0; k < 20; ++k) {
                float dd = cdv[wid][c16][k]; int jj = cjv[wid][c16][k];
                if (dd < d2) {
                    if (dd < d1) {
                        d2 = d1; i2 = i1;
                        if (dd < d0) { d1 = d0; i1 = i0; d0 = dd; i0 = jj; }
                        else         { d1 = dd; i1 = jj; }
                    } else { d2 = dd; i2 = jj; }
                }
            }
            if (srow < N) {
                float e1 = __expf(d0 - d1);
                float e2 = __expf(d0 - d2);
                float inv = 1.f / (1.f + e1 + e2);
                float w0 = inv, w1 = e1 * inv, w2 = e2 * inv;
                const float* p0 = tpts + 3 * (size_t)i0;
                const float* p1 = tpts + 3 * (size_t)i1;
                const float* p2 = tpts + 3 * (size_t)i2;
                out[3 * (size_t)srow + 0] = w0 * p0[0] + w1 * p1[0] + w2 * p2[0];
                out[3 * (size_t)srow + 1] = w0 * p0[1] + w1 * p1[1] + w2 * p2[1];
                out[3 * (size_t)srow + 2] = w0 * p0[2] + w1 * p1[2] + w2 * p2[2];
            }
        }
        __syncthreads();
    }
}

extern "C" void kernel_launch(void* const* d_in, const int* in_sizes, int n_in,
                              void* d_out, int out_size, void* d_ws, size_t ws_size,
                              hipStream_t stream) {
    const float* src  = (const float*)d_in[0];  // [N,128]
    const float* tgt  = (const float*)d_in[1];  // [M,128]
    const float* tpts = (const float*)d_in[2];  // [M,3]
    float* out = (float*)d_out;

    int N = in_sizes[0] / D;
    int M = in_sizes[1] / D;
    int Mpad = (M + 15) & ~15;

    unsigned short* tbf = (unsigned short*)d_ws;                 // Mpad*128 bf16 (-2*t), swizzled
    float* tsq = (float*)((char*)d_ws + (size_t)Mpad * D * 2);   // Mpad f32 (INF pads)

    prep_kernel<<<Mpad, 64, 0, stream>>>(tgt, tbf, tsq, M, Mpad);
    int per_block = WAVES * SRCS_PER_WAVE;                       // 128
    int nblk = (N + per_block - 1) / per_block;                  // 782
    knn_kernel<<<nblk, 256, 0, stream>>>(src, tbf, tsq, tgt, tpts, out, N, M, Mpad);
}

// Round 6
// 504.175 us; speedup vs baseline: 1.6091x; 1.3623x over previous
//
#include <hip/hip_runtime.h>
#include <math.h>

#define D 128
#define CT 2                       // source col-tiles (of 16) per wave
#define SRCS_PER_WAVE (CT * 16)    // 32
#define WAVES 4                    // waves per block; block covers 128 sources
#define BIAS 16.0f                 // keeps biased approx distance > 0 (u32 key ordering)

typedef __attribute__((ext_vector_type(8))) short short8;   // 8 bf16 = 4 VGPR
typedef __attribute__((ext_vector_type(4))) float f32x4;

// fp32 -> bf16 bits, round-to-nearest-even
static __device__ __forceinline__ unsigned short f2bf(float x) {
    unsigned u = __float_as_uint(x);
    unsigned r = u + 0x7FFFu + ((u >> 16) & 1u);
    return (unsigned short)(r >> 16);
}

// v_med3_u32: single-op per-level sorted insert primitive
static __device__ __forceinline__ unsigned med3u(unsigned a, unsigned b, unsigned c) {
    unsigned d;
    asm("v_med3_u32 %0, %1, %2, %3" : "=v"(d) : "v"(a), "v"(b), "v"(c));
    return d;
}

// exact sorted-ascending top-5 insert: 4 med3 + 1 min (top-down preserves deps)
static __device__ __forceinline__ void ins5(unsigned st[5], unsigned k) {
    st[4] = med3u(st[4], st[3], k);
    st[3] = med3u(st[3], st[2], k);
    st[2] = med3u(st[2], st[1], k);
    st[1] = med3u(st[1], st[0], k);
    st[0] = st[0] < k ? st[0] : k;
}

static __device__ __forceinline__ void gload_lds16(const void* g, void* l) {
    __builtin_amdgcn_global_load_lds(
        (const __attribute__((address_space(1))) unsigned*)g,
        (__attribute__((address_space(3))) unsigned*)l, 16, 0, 0);
}

// Phase 0: tgt (fp32) -> tbf = bf16(-2*tgt), PRE-SWIZZLED within each 16-row tile
// (16B-unit u of row r stored at u ^ (r&15)); pad rows (M..Mpad) zeros.
// tsqb = |t|^2 + BIAS (INF pads) for the hot loop; tsqe = exact |t|^2 for refine.
__global__ void prep_kernel(const float* __restrict__ tgt, unsigned short* __restrict__ tbf,
                            float* __restrict__ tsqb, float* __restrict__ tsqe,
                            int M, int Mpad) {
    int row  = blockIdx.x;
    int lane = threadIdx.x;  // 64; handles elems 2*lane, 2*lane+1
    if (row >= Mpad) return;
    float2 v = make_float2(0.f, 0.f);
    if (row < M) v = *(const float2*)(tgt + (size_t)row * D + lane * 2);
    unsigned pack = (unsigned)f2bf(-2.f * v.x) | ((unsigned)f2bf(-2.f * v.y) << 16);
    size_t byte = (size_t)row * 256 + (size_t)(((lane >> 2) ^ (row & 15)) * 16 + (lane & 3) * 4);
    *(unsigned*)((char*)tbf + byte) = pack;
    float ss = v.x * v.x + v.y * v.y;
    #pragma unroll
    for (int off = 1; off < 64; off <<= 1) ss += __shfl_xor(ss, off);
    if (lane == 0) {
        tsqe[row] = ss;
        tsqb[row] = (row < M) ? (ss + BIAS) : __builtin_inff();
    }
}

// Main: A = targets (64-row macro-tiles staged to LDS, double-buffered, one
// barrier per macro), B = sources (register-resident). acc init = tsqb[row];
// MFMA adds (-2t)·s => acc = biased shifted sq-distance. Top-5 packed keys
// (dist bits | 13-bit j) per thread per col-tile via med3 insert.
// Epilogue: exact fp32 re-rank of 20 candidates + softmax + output.
__global__ __launch_bounds__(256, 3)
void knn_kernel(const float* __restrict__ src, const unsigned short* __restrict__ tbf,
                const float* __restrict__ tsqb, const float* __restrict__ tsqe,
                const float* __restrict__ tgt, const float* __restrict__ tpts,
                float* __restrict__ out, int N, int M, int Mpad) {
    const int tid  = (int)threadIdx.x;
    const int wid  = tid >> 6;
    const int lane = tid & 63;
    const int c16  = lane & 15;   // MFMA col (source slot) / A-row within tile
    const int g    = lane >> 4;   // row-class (C rows 4g..4g+3)
    const int colbase = blockIdx.x * (WAVES * SRCS_PER_WAVE) + wid * SRCS_PER_WAVE;

    __shared__ short8 abuf[2][1024];        // 2 x 16KB double-buffered macro-tile (swizzled)
    __shared__ float cdv[WAVES][16][20];
    __shared__ int   cjv[WAVES][16][20];

    // ---- build source (B) fragments: bf16, k = kk*32 + g*8 + e (matches A packing)
    short8 bfrag[CT][4];
    #pragma unroll
    for (int ct = 0; ct < CT; ++ct) {
        int srow = colbase + ct * 16 + c16;
        if (srow >= N) srow = N - 1;
        const float* sp = src + (size_t)srow * D + g * 8;
        #pragma unroll
        for (int kk = 0; kk < 4; ++kk) {
            float4 v0 = *(const float4*)(sp + kk * 32);
            float4 v1 = *(const float4*)(sp + kk * 32 + 4);
            short8 b;
            b[0] = (short)f2bf(v0.x); b[1] = (short)f2bf(v0.y);
            b[2] = (short)f2bf(v0.z); b[3] = (short)f2bf(v0.w);
            b[4] = (short)f2bf(v1.x); b[5] = (short)f2bf(v1.y);
            b[6] = (short)f2bf(v1.z); b[7] = (short)f2bf(v1.w);
            bfrag[ct][kk] = b;
        }
    }

    unsigned st[CT][5];
    #pragma unroll
    for (int ct = 0; ct < CT; ++ct)
        #pragma unroll
        for (int s = 0; s < 5; ++s) st[ct][s] = 0xFFFFFFFFu;

    const int msteps = Mpad >> 6;           // 64 rows per macro-step

    // stage macro-tile t into buffer b: 16KB, each wave 4 x 1KB linear chunks
    #define STAGE(t, b)                                                              \
        do {                                                                         \
            const char* gbase_ = (const char*)tbf + (size_t)(t) * 16384;             \
            _Pragma("unroll")                                                        \
            for (int q_ = 0; q_ < 4; ++q_) {                                         \
                int uoff_ = q_ * 256 + wid * 64;                                     \
                gload_lds16(gbase_ + ((size_t)(uoff_ + lane)) * 16,                  \
                            (void*)&abuf[b][uoff_]);                                 \
            }                                                                        \
        } while (0)

    float4 qv[4], qn[4];
    #pragma unroll
    for (int s = 0; s < 4; ++s) qv[s] = *(const float4*)(tsqb + s * 16 + g * 4);
    STAGE(0, 0);
    __syncthreads();

    unsigned jb = (unsigned)(g * 4);
    int cur = 0;
    for (int t = 0; t < msteps; ++t) {
        int tpf = (t + 1 < msteps) ? (t + 1) : t;
        STAGE(tpf, cur ^ 1);
        #pragma unroll
        for (int s = 0; s < 4; ++s)
            qn[s] = *(const float4*)(tsqb + (size_t)tpf * 64 + s * 16 + g * 4);

        #pragma unroll
        for (int sub = 0; sub < 4; ++sub) {
            short8 a[4];
            #pragma unroll
            for (int kk = 0; kk < 4; ++kk)
                a[kk] = abuf[cur][sub * 256 + c16 * 16 + ((g + 4 * kk) ^ c16)];
            #pragma unroll
            for (int ct = 0; ct < CT; ++ct) {
                f32x4 acc = { qv[sub].x, qv[sub].y, qv[sub].z, qv[sub].w };
                #pragma unroll
                for (int kk = 0; kk < 4; ++kk)
                    acc = __builtin_amdgcn_mfma_f32_16x16x32_bf16(a[kk], bfrag[ct][kk], acc, 0, 0, 0);
                #pragma unroll
                for (int e = 0; e < 4; ++e) {
                    unsigned key = (__float_as_uint(acc[e]) & 0xFFFFE000u) | (jb + (unsigned)e);
                    ins5(st[ct], key);
                }
            }
            jb += 16;
        }
        #pragma unroll
        for (int s = 0; s < 4; ++s) qv[s] = qn[s];
        __syncthreads();   // drains vmcnt(0): next macro staged; buf[cur] consumed
        cur ^= 1;
    }

    // ---- exact fp32 refine of 20 candidates per source ----
    #pragma unroll
    for (int ct = 0; ct < CT; ++ct) {
        int js[5]; float dots[5];
        #pragma unroll
        for (int s = 0; s < 5; ++s) {
            int j = (int)(st[ct][s] & 0x1FFFu);
            js[s] = (j < M) ? j : (M - 1);
            dots[s] = 0.f;
        }
        int srow = colbase + ct * 16 + c16;
        int srcl = (srow < N) ? srow : (N - 1);
        const float* sp = src + (size_t)srcl * D;
        for (int kc = 0; kc < D / 16; ++kc) {
            float4 s0 = *(const float4*)(sp + kc * 16);
            float4 s1 = *(const float4*)(sp + kc * 16 + 4);
            float4 s2 = *(const float4*)(sp + kc * 16 + 8);
            float4 s3 = *(const float4*)(sp + kc * 16 + 12);
            #pragma unroll
            for (int s = 0; s < 5; ++s) {
                const float* tp = tgt + (size_t)js[s] * D + kc * 16;
                float4 t0 = *(const float4*)(tp);
                float4 t1 = *(const float4*)(tp + 4);
                float4 t2 = *(const float4*)(tp + 8);
                float4 t3 = *(const float4*)(tp + 12);
                float d = dots[s];
                d = fmaf(s0.x, t0.x, d); d = fmaf(s0.y, t0.y, d);
                d = fmaf(s0.z, t0.z, d); d = fmaf(s0.w, t0.w, d);
                d = fmaf(s1.x, t1.x, d); d = fmaf(s1.y, t1.y, d);
                d = fmaf(s1.z, t1.z, d); d = fmaf(s1.w, t1.w, d);
                d = fmaf(s2.x, t2.x, d); d = fmaf(s2.y, t2.y, d);
                d = fmaf(s2.z, t2.z, d); d = fmaf(s2.w, t2.w, d);
                d = fmaf(s3.x, t3.x, d); d = fmaf(s3.y, t3.y, d);
                d = fmaf(s3.z, t3.z, d); d = fmaf(s3.w, t3.w, d);
                dots[s] = d;
            }
        }
        #pragma unroll
        for (int s = 0; s < 5; ++s) {
            cdv[wid][c16][g * 5 + s] = fmaf(-2.f, dots[s], tsqe[js[s]]);
            cjv[wid][c16][g * 5 + s] = js[s];
        }
        __syncthreads();
        if (g == 0) {
            float d0 = __builtin_inff(), d1 = d0, d2 = d0;
            int i0 = 0, i1 = 0, i2 = 0;
            for (int k = 0; k < 20; ++k) {
                float dd = cdv[wid][c16][k]; int jj = cjv[wid][c16][k];
                if (dd < d2) {
                    if (dd < d1) {
                        d2 = d1; i2 = i1;
                        if (dd < d0) { d1 = d0; i1 = i0; d0 = dd; i0 = jj; }
                        else         { d1 = dd; i1 = jj; }
                    } else { d2 = dd; i2 = jj; }
                }
            }
            if (srow < N) {
                float e1 = __expf(d0 - d1);
                float e2 = __expf(d0 - d2);
                float inv = 1.f / (1.f + e1 + e2);
                float w0 = inv, w1 = e1 * inv, w2 = e2 * inv;
                const float* p0 = tpts + 3 * (size_t)i0;
                const float* p1 = tpts + 3 * (size_t)i1;
                const float* p2 = tpts + 3 * (size_t)i2;
                out[3 * (size_t)srow + 0] = w0 * p0[0] + w1 * p1[0] + w2 * p2[0];
                out[3 * (size_t)srow + 1] = w0 * p0[1] + w1 * p1[1] + w2 * p2[1];
                out[3 * (size_t)srow + 2] = w0 * p0[2] + w1 * p1[2] + w2 * p2[2];
            }
        }
        __syncthreads();
    }
}

extern "C" void kernel_launch(void* const* d_in, const int* in_sizes, int n_in,
                              void* d_out, int out_size, void* d_ws, size_t ws_size,
                              hipStream_t stream) {
    const float* src  = (const float*)d_in[0];  // [N,128]
    const float* tgt  = (const float*)d_in[1];  // [M,128]
    const float* tpts = (const float*)d_in[2];  // [M,3]
    float* out = (float*)d_out;

    int N = in_sizes[0] / D;
    int M = in_sizes[1] / D;
    int Mpad = (M + 63) & ~63;                  // 64-row macro-tiles

    unsigned short* tbf = (unsigned short*)d_ws;                      // Mpad*128 bf16 (-2t), swizzled
    float* tsqb = (float*)((char*)d_ws + (size_t)Mpad * D * 2);       // Mpad f32: |t|^2+BIAS (INF pads)
    float* tsqe = (float*)((char*)d_ws + (size_t)Mpad * D * 2 + (size_t)Mpad * 4);  // exact |t|^2

    prep_kernel<<<Mpad, 64, 0, stream>>>(tgt, tbf, tsqb, tsqe, M, Mpad);
    int per_block = WAVES * SRCS_PER_WAVE;                            // 128
    int nblk = (N + per_block - 1) / per_block;                       // 782
    knn_kernel<<<nblk, 256, 0, stream>>>(src, tbf, tsqb, tsqe, tgt, tpts, out, N, M, Mpad);
}

// Round 7
// 438.588 us; speedup vs baseline: 1.8498x; 1.1495x over previous
//
#include <hip/hip_runtime.h>
#include <math.h>

#define D 128
#define CT 2                       // source col-tiles (of 16) per wave
#define SRCS_PER_WAVE (CT * 16)    // 32
#define WAVES 4                    // waves per block; block covers 128 sources
#define BIAS 16.0f                 // keeps biased approx distance > 0 (u32 key ordering)

typedef __attribute__((ext_vector_type(8))) short short8;   // 8 bf16 = 4 VGPR
typedef __attribute__((ext_vector_type(4))) float f32x4;

// fp32 -> bf16 bits, round-to-nearest-even
static __device__ __forceinline__ unsigned short f2bf(float x) {
    unsigned u = __float_as_uint(x);
    unsigned r = u + 0x7FFFu + ((u >> 16) & 1u);
    return (unsigned short)(r >> 16);
}

// v_med3_u32: single-op per-level sorted insert primitive
static __device__ __forceinline__ unsigned med3u(unsigned a, unsigned b, unsigned c) {
    unsigned d;
    asm("v_med3_u32 %0, %1, %2, %3" : "=v"(d) : "v"(a), "v"(b), "v"(c));
    return d;
}

// exact sorted-ascending top-5 insert: 4 med3 + 1 min
static __device__ __forceinline__ void ins5(unsigned st[5], unsigned k) {
    st[4] = med3u(st[4], st[3], k);
    st[3] = med3u(st[3], st[2], k);
    st[2] = med3u(st[2], st[1], k);
    st[1] = med3u(st[1], st[0], k);
    st[0] = st[0] < k ? st[0] : k;
}

static __device__ __forceinline__ void gload_lds16(const void* g, void* l) {
    __builtin_amdgcn_global_load_lds(
        (const __attribute__((address_space(1))) unsigned*)g,
        (__attribute__((address_space(3))) unsigned*)l, 16, 0, 0);
}

// Phase 0: tgt (fp32) -> tbf = bf16(-2*tgt), PRE-SWIZZLED within each 16-row tile
// (16B-unit u of row r stored at u ^ (r&15)); pad rows (M..Mpad) zeros.
// tsqb = |t|^2 + BIAS (INF pads) for the hot loop; tsqe = exact |t|^2 for refine.
__global__ void prep_kernel(const float* __restrict__ tgt, unsigned short* __restrict__ tbf,
                            float* __restrict__ tsqb, float* __restrict__ tsqe,
                            int M, int Mpad) {
    int row  = blockIdx.x;
    int lane = threadIdx.x;  // 64; handles elems 2*lane, 2*lane+1
    if (row >= Mpad) return;
    float2 v = make_float2(0.f, 0.f);
    if (row < M) v = *(const float2*)(tgt + (size_t)row * D + lane * 2);
    unsigned pack = (unsigned)f2bf(-2.f * v.x) | ((unsigned)f2bf(-2.f * v.y) << 16);
    size_t byte = (size_t)row * 256 + (size_t)(((lane >> 2) ^ (row & 15)) * 16 + (lane & 3) * 4);
    *(unsigned*)((char*)tbf + byte) = pack;
    float ss = v.x * v.x + v.y * v.y;
    #pragma unroll
    for (int off = 1; off < 64; off <<= 1) ss += __shfl_xor(ss, off);
    if (lane == 0) {
        tsqe[row] = ss;
        tsqb[row] = (row < M) ? (ss + BIAS) : __builtin_inff();
    }
}

// Main: A = targets (64-row macro-tiles staged to LDS, double-buffered, one
// barrier per macro), B = sources (register-resident). acc init = tsqb[row];
// MFMA adds (-2t)·s => acc = biased shifted sq-distance. Top-5 packed keys
// (dist bits | 13-bit j) per thread per col-tile via med3 insert.
// Epilogue: exact fp32 re-rank of 20 candidates + softmax + output.
// Epilogue cdv/cjv OVERLAY the (dead-after-loop) abuf -> LDS = 32 KB exactly,
// 5 blocks/CU fit; grid 782 blocks all co-resident.
__global__ __launch_bounds__(256, 4)
void knn_kernel(const float* __restrict__ src, const unsigned short* __restrict__ tbf,
                const float* __restrict__ tsqb, const float* __restrict__ tsqe,
                const float* __restrict__ tgt, const float* __restrict__ tpts,
                float* __restrict__ out, int N, int M, int Mpad) {
    const int tid  = (int)threadIdx.x;
    const int wid  = tid >> 6;
    const int lane = tid & 63;
    const int c16  = lane & 15;   // MFMA col (source slot) / A-row within tile
    const int g    = lane >> 4;   // row-class (C rows 4g..4g+3)
    const int colbase = blockIdx.x * (WAVES * SRCS_PER_WAVE) + wid * SRCS_PER_WAVE;

    __shared__ __align__(16) char smem[32768];  // 2 x 16KB macro-tile; epilogue overlays
    short8 (*abuf)[1024] = reinterpret_cast<short8 (*)[1024]>(smem);
    float (*cdv)[16][20] = reinterpret_cast<float (*)[16][20]>(smem);                  // [WAVES][16][20]
    int   (*cjv)[16][20] = reinterpret_cast<int (*)[16][20]>(smem + WAVES*16*20*4);    // [WAVES][16][20]

    // ---- build source (B) fragments: bf16, k = kk*32 + g*8 + e (matches A packing)
    short8 bfrag[CT][4];
    #pragma unroll
    for (int ct = 0; ct < CT; ++ct) {
        int srow = colbase + ct * 16 + c16;
        if (srow >= N) srow = N - 1;
        const float* sp = src + (size_t)srow * D + g * 8;
        #pragma unroll
        for (int kk = 0; kk < 4; ++kk) {
            float4 v0 = *(const float4*)(sp + kk * 32);
            float4 v1 = *(const float4*)(sp + kk * 32 + 4);
            short8 b;
            b[0] = (short)f2bf(v0.x); b[1] = (short)f2bf(v0.y);
            b[2] = (short)f2bf(v0.z); b[3] = (short)f2bf(v0.w);
            b[4] = (short)f2bf(v1.x); b[5] = (short)f2bf(v1.y);
            b[6] = (short)f2bf(v1.z); b[7] = (short)f2bf(v1.w);
            bfrag[ct][kk] = b;
        }
    }

    unsigned st[CT][5];
    #pragma unroll
    for (int ct = 0; ct < CT; ++ct)
        #pragma unroll
        for (int s = 0; s < 5; ++s) st[ct][s] = 0xFFFFFFFFu;

    const int msteps = Mpad >> 6;           // 64 rows per macro-step

    // stage macro-tile t into buffer b: 16KB, each wave 4 x 1KB linear chunks
    #define STAGE(t, b)                                                              \
        do {                                                                         \
            const char* gbase_ = (const char*)tbf + (size_t)(t) * 16384;             \
            _Pragma("unroll")                                                        \
            for (int q_ = 0; q_ < 4; ++q_) {                                         \
                int uoff_ = q_ * 256 + wid * 64;                                     \
                gload_lds16(gbase_ + ((size_t)(uoff_ + lane)) * 16,                  \
                            (void*)&abuf[b][uoff_]);                                 \
            }                                                                        \
        } while (0)

    float4 qv[4], qn[4];
    #pragma unroll
    for (int s = 0; s < 4; ++s) qv[s] = *(const float4*)(tsqb + s * 16 + g * 4);
    STAGE(0, 0);
    __syncthreads();

    unsigned jb = (unsigned)(g * 4);
    int cur = 0;
    for (int t = 0; t < msteps; ++t) {
        int tpf = (t + 1 < msteps) ? (t + 1) : t;
        STAGE(tpf, cur ^ 1);
        #pragma unroll
        for (int s = 0; s < 4; ++s)
            qn[s] = *(const float4*)(tsqb + (size_t)tpf * 64 + s * 16 + g * 4);

        #pragma unroll
        for (int sub = 0; sub < 4; ++sub) {
            short8 a[4];
            #pragma unroll
            for (int kk = 0; kk < 4; ++kk)
                a[kk] = abuf[cur][sub * 256 + c16 * 16 + ((g + 4 * kk) ^ c16)];
            #pragma unroll
            for (int ct = 0; ct < CT; ++ct) {
                f32x4 acc = { qv[sub].x, qv[sub].y, qv[sub].z, qv[sub].w };
                #pragma unroll
                for (int kk = 0; kk < 4; ++kk)
                    acc = __builtin_amdgcn_mfma_f32_16x16x32_bf16(a[kk], bfrag[ct][kk], acc, 0, 0, 0);
                #pragma unroll
                for (int e = 0; e < 4; ++e) {
                    unsigned key = (__float_as_uint(acc[e]) & 0xFFFFE000u) | (jb + (unsigned)e);
                    ins5(st[ct], key);
                }
            }
            jb += 16;
        }
        #pragma unroll
        for (int s = 0; s < 4; ++s) qv[s] = qn[s];
        __syncthreads();   // drains vmcnt(0): next macro staged; buf[cur] consumed
        cur ^= 1;
    }
    // after this point abuf is dead (final barrier passed) -> overlay is safe

    // ---- exact fp32 refine of 20 candidates per source ----
    #pragma unroll
    for (int ct = 0; ct < CT; ++ct) {
        int js[5]; float dots[5];
        #pragma unroll
        for (int s = 0; s < 5; ++s) {
            int j = (int)(st[ct][s] & 0x1FFFu);
            js[s] = (j < M) ? j : (M - 1);
            dots[s] = 0.f;
        }
        int srow = colbase + ct * 16 + c16;
        int srcl = (srow < N) ? srow : (N - 1);
        const float* sp = src + (size_t)srcl * D;
        for (int kc = 0; kc < D / 16; ++kc) {
            float4 s0 = *(const float4*)(sp + kc * 16);
            float4 s1 = *(const float4*)(sp + kc * 16 + 4);
            float4 s2 = *(const float4*)(sp + kc * 16 + 8);
            float4 s3 = *(const float4*)(sp + kc * 16 + 12);
            #pragma unroll
            for (int s = 0; s < 5; ++s) {
                const float* tp = tgt + (size_t)js[s] * D + kc * 16;
                float4 t0 = *(const float4*)(tp);
                float4 t1 = *(const float4*)(tp + 4);
                float4 t2 = *(const float4*)(tp + 8);
                float4 t3 = *(const float4*)(tp + 12);
                float d = dots[s];
                d = fmaf(s0.x, t0.x, d); d = fmaf(s0.y, t0.y, d);
                d = fmaf(s0.z, t0.z, d); d = fmaf(s0.w, t0.w, d);
                d = fmaf(s1.x, t1.x, d); d = fmaf(s1.y, t1.y, d);
                d = fmaf(s1.z, t1.z, d); d = fmaf(s1.w, t1.w, d);
                d = fmaf(s2.x, t2.x, d); d = fmaf(s2.y, t2.y, d);
                d = fmaf(s2.z, t2.z, d); d = fmaf(s2.w, t2.w, d);
                d = fmaf(s3.x, t3.x, d); d = fmaf(s3.y, t3.y, d);
                d = fmaf(s3.z, t3.z, d); d = fmaf(s3.w, t3.w, d);
                dots[s] = d;
            }
        }
        #pragma unroll
        for (int s = 0; s < 5; ++s) {
            cdv[wid][c16][g * 5 + s] = fmaf(-2.f, dots[s], tsqe[js[s]]);
            cjv[wid][c16][g * 5 + s] = js[s];
        }
        __syncthreads();
        if (g == 0) {
            float d0 = __builtin_inff(), d1 = d0, d2 = d0;
            int i0 = 0, i1 = 0, i2 = 0;
            for (int k = 0; k < 20; ++k) {
                float dd = cdv[wid][c16][k]; int jj = cjv[wid][c16][k];
                if (dd < d2) {
                    if (dd < d1) {
                        d2 = d1; i2 = i1;
                        if (dd < d0) { d1 = d0; i1 = i0; d0 = dd; i0 = jj; }
                        else         { d1 = dd; i1 = jj; }
                    } else { d2 = dd; i2 = jj; }
                }
            }
            if (srow < N) {
                float e1 = __expf(d0 - d1);
                float e2 = __expf(d0 - d2);
                float inv = 1.f / (1.f + e1 + e2);
                float w0 = inv, w1 = e1 * inv, w2 = e2 * inv;
                const float* p0 = tpts + 3 * (size_t)i0;
                const float* p1 = tpts + 3 * (size_t)i1;
                const float* p2 = tpts + 3 * (size_t)i2;
                out[3 * (size_t)srow + 0] = w0 * p0[0] + w1 * p1[0] + w2 * p2[0];
                out[3 * (size_t)srow + 1] = w0 * p0[1] + w1 * p1[1] + w2 * p2[1];
                out[3 * (size_t)srow + 2] = w0 * p0[2] + w1 * p1[2] + w2 * p2[2];
            }
        }
        __syncthreads();
    }
}

extern "C" void kernel_launch(void* const* d_in, const int* in_sizes, int n_in,
                              void* d_out, int out_size, void* d_ws, size_t ws_size,
                              hipStream_t stream) {
    const float* src  = (const float*)d_in[0];  // [N,128]
    const float* tgt  = (const float*)d_in[1];  // [M,128]
    const float* tpts = (const float*)d_in[2];  // [M,3]
    float* out = (float*)d_out;

    int N = in_sizes[0] / D;
    int M = in_sizes[1] / D;
    int Mpad = (M + 63) & ~63;                  // 64-row macro-tiles

    unsigned short* tbf = (unsigned short*)d_ws;                      // Mpad*128 bf16 (-2t), swizzled
    float* tsqb = (float*)((char*)d_ws + (size_t)Mpad * D * 2);       // Mpad f32: |t|^2+BIAS (INF pads)
    float* tsqe = (float*)((char*)d_ws + (size_t)Mpad * D * 2 + (size_t)Mpad * 4);  // exact |t|^2

    prep_kernel<<<Mpad, 64, 0, stream>>>(tgt, tbf, tsqb, tsqe, M, Mpad);
    int per_block = WAVES * SRCS_PER_WAVE;                            // 128
    int nblk = (N + per_block - 1) / per_block;                       // 782
    knn_kernel<<<nblk, 256, 0, stream>>>(src, tbf, tsqb, tsqe, tgt, tpts, out, N, M, Mpad);
}